// Round 1
// baseline (847.463 us; speedup 1.0000x reference)
//
#include <hip/hip_runtime.h>
#include <math.h>

// ForwardSumLoss (CTC forward), MI355X — fused single kernel + tiny mean.
// One block per batch. Wave 0: 801-state recursion reformulated in (u,o)
// pairs: u[j]=a[2j]+a[2j-1], o[j]=a[2j+1]. Step: o'[j]=w_j*(o[j]+u[j]),
// u'[j]=fma(eb,u[j],o'[j-1]) -> 24 VALU/step (was 32), FMA on the even
// states, and the bpermute operand (o'[7]) is computed FIRST in the step
// while its consumer (u'[0]) is LAST, so consecutive bpermutes pipeline
// (independent over 7 steps; influence moves <=1 pair/step).
// Weights double-buffered in regs (wA/wB, compile-time selection).
// Waves 1-3: producers; global prefetch loads are now issued at the START
// of each chunk (before store/exp) so the s_waitcnt vmcnt(0) the compiler
// emits before s_barrier has ~500 cy of exp/LDS-store work to hide under.
// Final tail = a[2L]+a[2L-1] = u[L] directly.

namespace {
constexpr int kB = 64;
constexpr int kT = 2000;
constexpr int kL = 400;
constexpr int kC = 16;            // timesteps per chunk
constexpr int kRow = 408;         // floats per staged row (400 + 8 guard)
constexpr float kEblank = 0.36787944117144233f;   // exp(-1)
}

__global__ __launch_bounds__(256, 1) void ctc_forward_kernel(
        const float* __restrict__ attn, const int* __restrict__ text_lens,
        const int* __restrict__ mel_lens, float* __restrict__ loss_ws) {
    __shared__ __align__(16) float wbuf[2][kC][kRow];   // 52224 B
    __shared__ float psum[2][kC * 100];                 // 12800 B
    __shared__ double sLd;

    const int b    = blockIdx.x;
    const int tid  = threadIdx.x;
    const int lane = tid & 63;
    const int wv   = tid >> 6;
    const int Lb = text_lens[b];
    const int Tb = mel_lens[b];
    const int nck = (Tb + kC - 1) / kC;

    const float4* __restrict__ rp4 = (const float4*)(attn + (size_t)b * kT * kL);

    // guard zeros: words [400,408) of every row, both slots (256 writes)
    {
        const int slot = tid >> 7, row = (tid >> 3) & 15, j = tid & 7;
        wbuf[slot][row][400 + j] = 0.f;
    }

    // ---------------- producers (waves 1-3) ----------------
    const int pid = tid - 64;          // 0..191
    float4 rgE[9], rgO[9];             // STATIC buffers — never runtime-indexed

    auto load_chunk = [&](int ck, float4 (&rg)[9]) {
        const int t0 = ck * kC;
        #pragma unroll
        for (int i = 0; i < 9; ++i) {
            const int task = pid + 192 * i;
            if (task < kC * 100) {
                const int r = task / 100, q = task - r * 100;
                if (t0 + r < Tb) rg[i] = rp4[(size_t)(t0 + r) * 100 + q];
            }
        }
    };
    auto store_chunk = [&](int ck, const float4 (&rg)[9]) {
        const int slot = ck & 1;
        const int t0 = ck * kC;
        #pragma unroll
        for (int i = 0; i < 9; ++i) {
            const int task = pid + 192 * i;
            if (task < kC * 100) {
                const int r = task / 100, q = task - r * 100;
                float s4 = 0.f;
                if (t0 + r < Tb) {
                    const float4 x = rg[i];
                    const float e0 = __expf(x.x), e1 = __expf(x.y);
                    const float e2 = __expf(x.z), e3 = __expf(x.w);
                    s4 = (e0 + e1) + (e2 + e3);           // unmasked: denominator
                    const int l0 = 4 * q;
                    float4 w4;                            // masked: recursion
                    w4.x = (l0 + 0 < Lb) ? e0 : 0.f;
                    w4.y = (l0 + 1 < Lb) ? e1 : 0.f;
                    w4.z = (l0 + 2 < Lb) ? e2 : 0.f;
                    w4.w = (l0 + 3 < Lb) ? e3 : 0.f;
                    *(float4*)&wbuf[slot][r][4 * q] = w4;
                }
                psum[slot][task] = s4;
            }
        }
    };

    double Ld = 0.0;   // sum over t of log(se_t) — wave 1
    auto reduce_lse = [&](int ck) {
        const int ps = ck & 1;
        const int r = lane >> 2, k = lane & 3;   // 16 rows x 4 lanes
        float s = 0.f;
        #pragma unroll
        for (int m = 0; m < 25; ++m) s += psum[ps][r * 100 + k + 4 * m];
        s += __shfl_xor(s, 1);
        s += __shfl_xor(s, 2);
        float lv = (k == 0 && (ck * kC + r) < Tb) ? __logf(s + kEblank) : 0.f;
        lv += __shfl_xor(lv, 4);
        lv += __shfl_xor(lv, 8);
        lv += __shfl_xor(lv, 16);
        lv += __shfl_xor(lv, 32);
        Ld += (double)lv;
    };

    // ---------------- consumer (wave 0) ----------------
    const int gi  = (lane < 50) ? lane : 50;     // weight group (50 = guards)
    const int bpa = ((lane - 1) & 63) << 2;      // lane 0 reads lane 63 == 0
    float u[8], o[8];
    #pragma unroll
    for (int i = 0; i < 8; ++i) { u[i] = 0.f; o[i] = 0.f; }
    double Ct = 0.0;      // applied log-rescales
    float red = 1.0f;     // in-flight rescale reduction (neutral)
    float wA[8], wB[8];   // double-buffered step weights (static selection)

#define LOADW(W, PTR)                                  \
    {                                                  \
        *(float4*)&W[0] = *(const float4*)(PTR);       \
        *(float4*)&W[4] = *(const float4*)((PTR) + 4); \
    }

// One timestep in (u,o) form. WC = this step's weights; if DOLOAD, prefetch
// next step's weights from NPTR into WN while the bpermute is in flight.
#define STEP_UO(WC, WN, NPTR, DOLOAD)                                    \
    {                                                                    \
        const float op7 = WC[7] * (o[7] + u[7]);                         \
        const float p = __int_as_float(                                  \
            __builtin_amdgcn_ds_bpermute(bpa, __float_as_int(op7)));     \
        if (DOLOAD) LOADW(WN, NPTR);                                     \
        const float op0 = WC[0] * (o[0] + u[0]);                         \
        const float op1 = WC[1] * (o[1] + u[1]);                         \
        const float op2 = WC[2] * (o[2] + u[2]);                         \
        const float op3 = WC[3] * (o[3] + u[3]);                         \
        const float op4 = WC[4] * (o[4] + u[4]);                         \
        const float op5 = WC[5] * (o[5] + u[5]);                         \
        const float op6 = WC[6] * (o[6] + u[6]);                         \
        u[7] = __builtin_fmaf(kEblank, u[7], op6);                       \
        u[6] = __builtin_fmaf(kEblank, u[6], op5);                       \
        u[5] = __builtin_fmaf(kEblank, u[5], op4);                       \
        u[4] = __builtin_fmaf(kEblank, u[4], op3);                       \
        u[3] = __builtin_fmaf(kEblank, u[3], op2);                       \
        u[2] = __builtin_fmaf(kEblank, u[2], op1);                       \
        u[1] = __builtin_fmaf(kEblank, u[1], op0);                       \
        u[0] = __builtin_fmaf(kEblank, u[0], p);                         \
        o[0] = op0; o[1] = op1; o[2] = op2; o[3] = op3;                  \
        o[4] = op4; o[5] = op5; o[6] = op6; o[7] = op7;                  \
    }

    auto fold = [&]() {            // apply the just-completed reduction
        const float tot = red;
        const float c = 1.0f / tot;
        Ct += (double)__logf(tot);
        float ns = 0.f;
        #pragma unroll
        for (int i = 0; i < 8; ++i) {
            u[i] *= c; o[i] *= c;
            ns += u[i] + o[i];
        }
        red = ns;                  // new snapshot; butterfly runs next chunk
    };

    auto consumer_chunk = [&](int ck) {
        const float* wr = &wbuf[ck & 1][0][8 * gi];
        if (ck == 0) {
            if (lane == 0) { u[0] = kEblank; o[0] = wbuf[0][0][0]; }
            LOADW(wA, wr + kRow);                 // weights for t=1
            STEP_UO(wA, wB, wr + 2 * kRow, 1)     // t=1
            STEP_UO(wB, wA, wr + 3 * kRow, 1)
            STEP_UO(wA, wB, wr + 4 * kRow, 1)
            STEP_UO(wB, wA, wr + 5 * kRow, 1)
            STEP_UO(wA, wB, wr + 6 * kRow, 1)
            STEP_UO(wB, wA, wr + 7 * kRow, 1)
            STEP_UO(wA, wB, wr + 8 * kRow, 1)
            STEP_UO(wB, wA, wr + 9 * kRow, 1)
            STEP_UO(wA, wB, wr + 10 * kRow, 1)
            STEP_UO(wB, wA, wr + 11 * kRow, 1)
            STEP_UO(wA, wB, wr + 12 * kRow, 1)
            STEP_UO(wB, wA, wr + 13 * kRow, 1)
            STEP_UO(wA, wB, wr + 14 * kRow, 1)
            STEP_UO(wB, wA, wr + 15 * kRow, 1)
            STEP_UO(wA, wB, wr, 0)                // t=15 (no prefetch)
            fold();                               // tot==1 no-op + snapshot
        } else if (ck < nck - 1) {                // full chunk, branch-free
            LOADW(wA, wr);                        // weights for r=0
            STEP_UO(wA, wB, wr + 1 * kRow, 1)  red += __shfl_xor(red, 1);
            STEP_UO(wB, wA, wr + 2 * kRow, 1)  red += __shfl_xor(red, 2);
            STEP_UO(wA, wB, wr + 3 * kRow, 1)  red += __shfl_xor(red, 4);
            STEP_UO(wB, wA, wr + 4 * kRow, 1)  red += __shfl_xor(red, 8);
            STEP_UO(wA, wB, wr + 5 * kRow, 1)  red += __shfl_xor(red, 16);
            STEP_UO(wB, wA, wr + 6 * kRow, 1)  red += __shfl_xor(red, 32);
            STEP_UO(wA, wB, wr + 7 * kRow, 1)
            STEP_UO(wB, wA, wr + 8 * kRow, 1)
            STEP_UO(wA, wB, wr + 9 * kRow, 1)
            STEP_UO(wB, wA, wr + 10 * kRow, 1)
            STEP_UO(wA, wB, wr + 11 * kRow, 1)
            STEP_UO(wB, wA, wr + 12 * kRow, 1)
            STEP_UO(wA, wB, wr + 13 * kRow, 1)
            STEP_UO(wB, wA, wr + 14 * kRow, 1)
            STEP_UO(wA, wB, wr + 15 * kRow, 1)
            STEP_UO(wB, wA, wr, 0)                // r=15 (no prefetch)
            fold();
        } else {                                  // tail chunk (guarded)
            const int t0 = ck * kC;
            for (int r = 0; r < kC; ++r) {
                if (t0 + r >= Tb) break;
                const float* ww = wr + r * kRow;
                LOADW(wA, ww);
                STEP_UO(wA, wB, ww, 0)
            }
        }
    };

    // preamble: stage chunk 0, prefetch chunk 1
    if (wv > 0) {
        load_chunk(0, rgE);
        store_chunk(0, rgE);
        load_chunk(1, rgO);
    }
    __syncthreads();

    for (int ck = 0; ck < nck; ck += 2) {
        // even chunk ck: consumer reads slot 0; producers fill slot 1.
        // Producers issue next-next prefetch FIRST so the vmcnt(0) drain at
        // the barrier is hidden under the exp/LDS-store work.
        if (wv == 0) {
            consumer_chunk(ck);
        } else {
            load_chunk(ck + 2, rgE);               // guarded by t < Tb inside
            if (ck + 1 < nck) store_chunk(ck + 1, rgO);
            if (wv == 1) reduce_lse(ck);
        }
        __syncthreads();
        // odd chunk ck+1: consumer reads slot 1; producers fill slot 0
        if (ck + 1 < nck) {
            if (wv == 0) {
                consumer_chunk(ck + 1);
            } else {
                load_chunk(ck + 3, rgO);
                if (ck + 2 < nck) store_chunk(ck + 2, rgE);
                if (wv == 1) reduce_lse(ck + 1);
            }
            __syncthreads();
        }
    }

    // ---------------- epilogue ----------------
    // Final tail = a[2Lb] + a[2Lb-1] = u[Lb] directly.
    float* afin = (float*)wbuf;    // wbuf is dead now
    if (wv == 0 && lane <= 50) {
        #pragma unroll
        for (int i = 0; i < 8; ++i) afin[8 * lane + i] = u[i];
    }
    if (wv == 1 && lane == 0) sLd = Ld;
    __syncthreads();
    if (tid == 0) {
        const float tail = afin[Lb];
        const double la = (double)__logf(tail) + Ct - sLd;  // -inf if tail==0
        float loss = 0.f;
        if (la > -5e29) loss = (float)(-la / (double)Lb);
        loss_ws[b] = loss;
    }
#undef STEP_UO
#undef LOADW
}

__global__ void mean64_kernel(const float* __restrict__ loss_ws,
                              float* __restrict__ out) {
    float v = loss_ws[threadIdx.x];
    #pragma unroll
    for (int off = 32; off > 0; off >>= 1) v += __shfl_xor(v, off);
    if (threadIdx.x == 0) out[0] = v * (1.0f / 64.0f);
}

extern "C" void kernel_launch(void* const* d_in, const int* in_sizes, int n_in,
                              void* d_out, int out_size, void* d_ws, size_t ws_size,
                              hipStream_t stream) {
    const float* attn      = (const float*)d_in[0];
    const int*   text_lens = (const int*)d_in[1];
    const int*   mel_lens  = (const int*)d_in[2];
    float* loss_ws = (float*)d_ws;

    ctc_forward_kernel<<<kB, 256, 0, stream>>>(attn, text_lens, mel_lens, loss_ws);
    mean64_kernel<<<1, 64, 0, stream>>>(loss_ws, (float*)d_out);
}

// Round 2
// 801.160 us; speedup vs baseline: 1.0578x; 1.0578x over previous
//
#include <hip/hip_runtime.h>
#include <math.h>

// ForwardSumLoss (CTC forward), MI355X — fused single kernel + tiny mean.
// One block per batch. Wave 0: 801-state recursion in (u,o) pair form:
// u[j]=a[2j]+a[2j-1], o[j]=a[2j+1]. Step: o'[j]=w_j*(o[j]+u[j]),
// u'[j]=fma(eb,u[j],o'[j-1]), u'[0]=fma(eb,u[0],bperm(o'[7])).
// 24 VALU/step (was 32), bpermute operand computed FIRST / consumed LAST
// (~20 VALU slack hides the LDS round-trip). Weights are fresh per-step
// float4 locals (NOT a persistent double-buffer) so the compiler keeps its
// deep cross-step LDS-load pipelining — the R1 explicit wA/wB buffer
// serialized the pipeline to depth 1 and regressed 344->646us.
// Producers (waves 1-3): identical to the proven 344us structure
// (store_chunk first, load_chunk after). Wave 1 also reduces softmax
// denominators. Final tail = a[2L]+a[2L-1] = u[L] directly.

namespace {
constexpr int kB = 64;
constexpr int kT = 2000;
constexpr int kL = 400;
constexpr int kC = 16;            // timesteps per chunk
constexpr int kRow = 408;         // floats per staged row (400 + 8 guard)
constexpr float kEblank = 0.36787944117144233f;   // exp(-1)
}

__global__ __launch_bounds__(256, 1) void ctc_forward_kernel(
        const float* __restrict__ attn, const int* __restrict__ text_lens,
        const int* __restrict__ mel_lens, float* __restrict__ loss_ws) {
    __shared__ __align__(16) float wbuf[2][kC][kRow];   // 52224 B
    __shared__ float psum[2][kC * 100];                 // 12800 B
    __shared__ double sLd;

    const int b    = blockIdx.x;
    const int tid  = threadIdx.x;
    const int lane = tid & 63;
    const int wv   = tid >> 6;
    const int Lb = text_lens[b];
    const int Tb = mel_lens[b];
    const int nck = (Tb + kC - 1) / kC;

    const float4* __restrict__ rp4 = (const float4*)(attn + (size_t)b * kT * kL);

    // guard zeros: words [400,408) of every row, both slots (256 writes)
    {
        const int slot = tid >> 7, row = (tid >> 3) & 15, j = tid & 7;
        wbuf[slot][row][400 + j] = 0.f;
    }

    // ---------------- producers (waves 1-3) ----------------
    const int pid = tid - 64;          // 0..191
    float4 rgE[9], rgO[9];             // STATIC buffers — never runtime-indexed

    auto load_chunk = [&](int ck, float4 (&rg)[9]) {
        const int t0 = ck * kC;
        #pragma unroll
        for (int i = 0; i < 9; ++i) {
            const int task = pid + 192 * i;
            if (task < kC * 100) {
                const int r = task / 100, q = task - r * 100;
                if (t0 + r < Tb) rg[i] = rp4[(size_t)(t0 + r) * 100 + q];
            }
        }
    };
    auto store_chunk = [&](int ck, const float4 (&rg)[9]) {
        const int slot = ck & 1;
        const int t0 = ck * kC;
        #pragma unroll
        for (int i = 0; i < 9; ++i) {
            const int task = pid + 192 * i;
            if (task < kC * 100) {
                const int r = task / 100, q = task - r * 100;
                float s4 = 0.f;
                if (t0 + r < Tb) {
                    const float4 x = rg[i];
                    const float e0 = __expf(x.x), e1 = __expf(x.y);
                    const float e2 = __expf(x.z), e3 = __expf(x.w);
                    s4 = (e0 + e1) + (e2 + e3);           // unmasked: denominator
                    const int l0 = 4 * q;
                    float4 w4;                            // masked: recursion
                    w4.x = (l0 + 0 < Lb) ? e0 : 0.f;
                    w4.y = (l0 + 1 < Lb) ? e1 : 0.f;
                    w4.z = (l0 + 2 < Lb) ? e2 : 0.f;
                    w4.w = (l0 + 3 < Lb) ? e3 : 0.f;
                    *(float4*)&wbuf[slot][r][4 * q] = w4;
                }
                psum[slot][task] = s4;
            }
        }
    };

    double Ld = 0.0;   // sum over t of log(se_t) — wave 1
    auto reduce_lse = [&](int ck) {
        const int ps = ck & 1;
        const int r = lane >> 2, k = lane & 3;   // 16 rows x 4 lanes
        float s = 0.f;
        #pragma unroll
        for (int m = 0; m < 25; ++m) s += psum[ps][r * 100 + k + 4 * m];
        s += __shfl_xor(s, 1);
        s += __shfl_xor(s, 2);
        float lv = (k == 0 && (ck * kC + r) < Tb) ? __logf(s + kEblank) : 0.f;
        lv += __shfl_xor(lv, 4);
        lv += __shfl_xor(lv, 8);
        lv += __shfl_xor(lv, 16);
        lv += __shfl_xor(lv, 32);
        Ld += (double)lv;
    };

    // ---------------- consumer (wave 0) ----------------
    const int gi  = (lane < 50) ? lane : 50;     // weight group (50 = guards)
    const int bpa = ((lane - 1) & 63) << 2;      // lane 0 reads lane 63 == 0
    float u[8], o[8];
    #pragma unroll
    for (int i = 0; i < 8; ++i) { u[i] = 0.f; o[i] = 0.f; }
    double Ct = 0.0;      // applied log-rescales
    float red = 1.0f;     // in-flight rescale reduction (neutral)

    // One timestep in (u,o) form. Fresh float4 weight locals each call —
    // renameable, so the compiler pipelines the LDS loads across the
    // unrolled steps. op7 first (bperm input), p consumed last (u[0]).
    auto step = [&](const float* __restrict__ wr_row) {
        const float4 wlo = *(const float4*)(wr_row);
        const float4 whi = *(const float4*)(wr_row + 4);
        const float op7 = whi.w * (o[7] + u[7]);
        const float p = __int_as_float(
            __builtin_amdgcn_ds_bpermute(bpa, __float_as_int(op7)));
        const float op0 = wlo.x * (o[0] + u[0]);
        const float op1 = wlo.y * (o[1] + u[1]);
        const float op2 = wlo.z * (o[2] + u[2]);
        const float op3 = wlo.w * (o[3] + u[3]);
        const float op4 = whi.x * (o[4] + u[4]);
        const float op5 = whi.y * (o[5] + u[5]);
        const float op6 = whi.z * (o[6] + u[6]);
        u[7] = __builtin_fmaf(kEblank, u[7], op6);
        u[6] = __builtin_fmaf(kEblank, u[6], op5);
        u[5] = __builtin_fmaf(kEblank, u[5], op4);
        u[4] = __builtin_fmaf(kEblank, u[4], op3);
        u[3] = __builtin_fmaf(kEblank, u[3], op2);
        u[2] = __builtin_fmaf(kEblank, u[2], op1);
        u[1] = __builtin_fmaf(kEblank, u[1], op0);
        u[0] = __builtin_fmaf(kEblank, u[0], p);
        o[0] = op0; o[1] = op1; o[2] = op2; o[3] = op3;
        o[4] = op4; o[5] = op5; o[6] = op6; o[7] = op7;
    };
    auto fold = [&]() {            // apply the just-completed reduction
        const float tot = red;
        const float c = 1.0f / tot;
        Ct += (double)__logf(tot);
        float ns = 0.f;
        #pragma unroll
        for (int i = 0; i < 8; ++i) {
            u[i] *= c; o[i] *= c;
            ns += u[i] + o[i];
        }
        red = ns;                  // new snapshot; butterfly runs next chunk
    };
    auto consumer_chunk = [&](int ck) {
        const float* wr = &wbuf[ck & 1][0][8 * gi];
        if (ck == 0) {
            if (lane == 0) { u[0] = kEblank; o[0] = wbuf[0][0][0]; }
            #pragma unroll
            for (int r = 1; r < kC; ++r) step(wr + r * kRow);
            fold();                               // tot==1 no-op + snapshot
        } else if (ck < nck - 1) {                // full chunk, branch-free
            step(wr);             red += __shfl_xor(red, 1);
            step(wr + kRow);      red += __shfl_xor(red, 2);
            step(wr + 2 * kRow);  red += __shfl_xor(red, 4);
            step(wr + 3 * kRow);  red += __shfl_xor(red, 8);
            step(wr + 4 * kRow);  red += __shfl_xor(red, 16);
            step(wr + 5 * kRow);  red += __shfl_xor(red, 32);
            #pragma unroll
            for (int r = 6; r < kC; ++r) step(wr + r * kRow);
            fold();
        } else {                                  // tail chunk (guarded)
            const int t0 = ck * kC;
            for (int r = 0; r < kC; ++r) {
                if (t0 + r >= Tb) break;
                step(wr + r * kRow);
            }
        }
    };

    // preamble: stage chunk 0, prefetch chunk 1
    if (wv > 0) {
        load_chunk(0, rgE);
        store_chunk(0, rgE);
        load_chunk(1, rgO);
    }
    __syncthreads();

    for (int ck = 0; ck < nck; ck += 2) {
        // even chunk ck: consumer reads slot 0; producers fill slot 1
        if (wv == 0) {
            consumer_chunk(ck);
        } else {
            if (ck + 1 < nck) store_chunk(ck + 1, rgO);
            load_chunk(ck + 2, rgE);               // guarded by t < Tb inside
            if (wv == 1) reduce_lse(ck);
        }
        __syncthreads();
        // odd chunk ck+1: consumer reads slot 1; producers fill slot 0
        if (ck + 1 < nck) {
            if (wv == 0) {
                consumer_chunk(ck + 1);
            } else {
                if (ck + 2 < nck) store_chunk(ck + 2, rgE);
                load_chunk(ck + 3, rgO);
                if (wv == 1) reduce_lse(ck + 1);
            }
            __syncthreads();
        }
    }

    // ---------------- epilogue ----------------
    // Final tail = a[2Lb] + a[2Lb-1] = u at global pair index Lb.
    float* afin = (float*)wbuf;    // wbuf is dead now
    if (wv == 0 && lane <= 50) {
        #pragma unroll
        for (int i = 0; i < 8; ++i) afin[8 * lane + i] = u[i];
    }
    if (wv == 1 && lane == 0) sLd = Ld;
    __syncthreads();
    if (tid == 0) {
        const float tail = afin[Lb];
        const double la = (double)__logf(tail) + Ct - sLd;  // -inf if tail==0
        float loss = 0.f;
        if (la > -5e29) loss = (float)(-la / (double)Lb);
        loss_ws[b] = loss;
    }
}

__global__ void mean64_kernel(const float* __restrict__ loss_ws,
                              float* __restrict__ out) {
    float v = loss_ws[threadIdx.x];
    #pragma unroll
    for (int off = 32; off > 0; off >>= 1) v += __shfl_xor(v, off);
    if (threadIdx.x == 0) out[0] = v * (1.0f / 64.0f);
}

extern "C" void kernel_launch(void* const* d_in, const int* in_sizes, int n_in,
                              void* d_out, int out_size, void* d_ws, size_t ws_size,
                              hipStream_t stream) {
    const float* attn      = (const float*)d_in[0];
    const int*   text_lens = (const int*)d_in[1];
    const int*   mel_lens  = (const int*)d_in[2];
    float* loss_ws = (float*)d_ws;

    ctc_forward_kernel<<<kB, 256, 0, stream>>>(attn, text_lens, mel_lens, loss_ws);
    mean64_kernel<<<1, 64, 0, stream>>>(loss_ws, (float*)d_out);
}

// Round 4
// 541.832 us; speedup vs baseline: 1.5641x; 1.4786x over previous
//
#include <hip/hip_runtime.h>
#include <math.h>

// ForwardSumLoss (CTC forward), MI355X — fused single kernel + tiny mean.
// One block per batch. Wave 0: 801-state recursion in registers (16/lane),
// cross-lane hop done in the VALU domain with a single DPP wave_shr:1
// (ctrl 0x138, bound_ctrl -> lane 0 gets 0). This removes the per-step
// ds_bpermute LDS round-trip AND the per-step lgkmcnt(0) drain that sat
// between the weight ds_reads and their consumers — the weight prefetch
// can now stay in flight across steps.
// [R1/R2 lesson: the (u,o) basis makes the cross-lane value depend on the
// CURRENT step's ds_read -> serialized LDS chain, 344->596us. Reverted.]
// [R3 lesson: __builtin_amdgcn_writelane doesn't exist; wave_shr:1 DPP
// does the full-wave shift in one instruction anyway.]
// Waves 1-3: producers (load+exp+stage odd-state weights, contiguous
// 408-float rows, STATIC register prefetch buffers rgE/rgO). Wave 1 also
// reduces per-row softmax denominators into sum(log se).

namespace {
constexpr int kB = 64;
constexpr int kT = 2000;
constexpr int kL = 400;
constexpr int kC = 16;            // timesteps per chunk
constexpr int kRow = 408;         // floats per staged row (400 + 8 guard)
constexpr float kEblank = 0.36787944117144233f;   // exp(-1)
}

__global__ __launch_bounds__(256, 1) void ctc_forward_kernel(
        const float* __restrict__ attn, const int* __restrict__ text_lens,
        const int* __restrict__ mel_lens, float* __restrict__ loss_ws) {
    __shared__ __align__(16) float wbuf[2][kC][kRow];   // 52224 B
    __shared__ float psum[2][kC * 100];                 // 12800 B
    __shared__ double sLd;

    const int b    = blockIdx.x;
    const int tid  = threadIdx.x;
    const int lane = tid & 63;
    const int wv   = tid >> 6;
    const int Lb = text_lens[b];
    const int Tb = mel_lens[b];
    const int Sb = 2 * Lb + 1;
    const int nck = (Tb + kC - 1) / kC;

    const float4* __restrict__ rp4 = (const float4*)(attn + (size_t)b * kT * kL);

    // guard zeros: words [400,408) of every row, both slots (256 writes)
    {
        const int slot = tid >> 7, row = (tid >> 3) & 15, j = tid & 7;
        wbuf[slot][row][400 + j] = 0.f;
    }

    // ---------------- producers (waves 1-3) ----------------
    const int pid = tid - 64;          // 0..191
    float4 rgE[9], rgO[9];             // STATIC buffers — never runtime-indexed

    auto load_chunk = [&](int ck, float4 (&rg)[9]) {
        const int t0 = ck * kC;
        #pragma unroll
        for (int i = 0; i < 9; ++i) {
            const int task = pid + 192 * i;
            if (task < kC * 100) {
                const int r = task / 100, q = task - r * 100;
                if (t0 + r < Tb) rg[i] = rp4[(size_t)(t0 + r) * 100 + q];
            }
        }
    };
    auto store_chunk = [&](int ck, const float4 (&rg)[9]) {
        const int slot = ck & 1;
        const int t0 = ck * kC;
        #pragma unroll
        for (int i = 0; i < 9; ++i) {
            const int task = pid + 192 * i;
            if (task < kC * 100) {
                const int r = task / 100, q = task - r * 100;
                float s4 = 0.f;
                if (t0 + r < Tb) {
                    const float4 x = rg[i];
                    const float e0 = __expf(x.x), e1 = __expf(x.y);
                    const float e2 = __expf(x.z), e3 = __expf(x.w);
                    s4 = (e0 + e1) + (e2 + e3);           // unmasked: denominator
                    const int l0 = 4 * q;
                    float4 w4;                            // masked: recursion
                    w4.x = (l0 + 0 < Lb) ? e0 : 0.f;
                    w4.y = (l0 + 1 < Lb) ? e1 : 0.f;
                    w4.z = (l0 + 2 < Lb) ? e2 : 0.f;
                    w4.w = (l0 + 3 < Lb) ? e3 : 0.f;
                    *(float4*)&wbuf[slot][r][4 * q] = w4;
                }
                psum[slot][task] = s4;
            }
        }
    };

    double Ld = 0.0;   // sum over t of log(se_t) — wave 1
    auto reduce_lse = [&](int ck) {
        const int ps = ck & 1;
        const int r = lane >> 2, k = lane & 3;   // 16 rows x 4 lanes
        float s = 0.f;
        #pragma unroll
        for (int m = 0; m < 25; ++m) s += psum[ps][r * 100 + k + 4 * m];
        s += __shfl_xor(s, 1);
        s += __shfl_xor(s, 2);
        float lv = (k == 0 && (ck * kC + r) < Tb) ? __logf(s + kEblank) : 0.f;
        lv += __shfl_xor(lv, 4);
        lv += __shfl_xor(lv, 8);
        lv += __shfl_xor(lv, 16);
        lv += __shfl_xor(lv, 32);
        Ld += (double)lv;
    };

    // ---------------- consumer (wave 0) ----------------
    const int gi  = (lane < 50) ? lane : 50;     // weight group (50 = guards)
    float a[16];
    #pragma unroll
    for (int i = 0; i < 16; ++i) a[i] = 0.f;
    double Ct = 0.0;      // applied log-rescales
    float red = 1.0f;     // in-flight rescale reduction (neutral)

    // lane-1 shift, pure VALU: single DPP wave_shr:1 (0x138) across all 64
    // lanes; bound_ctrl=true -> lane 0 (invalid source) reads 0.
    auto shift1 = [&](float x) -> float {
        return __int_as_float(__builtin_amdgcn_update_dpp(
            0, __float_as_int(x), 0x138, 0xf, 0xf, true));
    };

    auto step = [&](const float* __restrict__ wr) {
        float w[8];
        *(float4*)&w[0] = *(const float4*)(wr);
        *(float4*)&w[4] = *(const float4*)(wr + 4);
        const float p1 = shift1(a[15]);
        float n[16];
        {
            const float s = a[0] + p1;
            n[0] = kEblank * s;
            n[1] = w[0] * (a[1] + s);
        }
        #pragma unroll
        for (int j = 1; j < 8; ++j) {
            const float s = a[2 * j] + a[2 * j - 1];
            n[2 * j]     = kEblank * s;
            n[2 * j + 1] = w[j] * (a[2 * j + 1] + s);
        }
        #pragma unroll
        for (int i = 0; i < 16; ++i) a[i] = n[i];
    };
    auto fold = [&]() {            // apply the just-completed reduction
        const float tot = red;
        const float c = 1.0f / tot;
        Ct += (double)__logf(tot);
        float ns = 0.f;
        #pragma unroll
        for (int i = 0; i < 16; ++i) { a[i] *= c; ns += a[i]; }
        red = ns;                  // new snapshot; butterfly runs next chunk
    };
    auto consumer_chunk = [&](int ck) {
        const float* wr = &wbuf[ck & 1][0][8 * gi];
        if (ck == 0) {
            if (lane == 0) { a[0] = kEblank; a[1] = wbuf[0][0][0]; }
            #pragma unroll
            for (int r = 1; r < kC; ++r) step(wr + r * kRow);
            fold();                               // tot==1 no-op + snapshot
        } else if (ck < nck - 1) {                // full chunk, branch-free
            step(wr);             red += __shfl_xor(red, 1);
            step(wr + kRow);      red += __shfl_xor(red, 2);
            step(wr + 2 * kRow);  red += __shfl_xor(red, 4);
            step(wr + 3 * kRow);  red += __shfl_xor(red, 8);
            step(wr + 4 * kRow);  red += __shfl_xor(red, 16);
            step(wr + 5 * kRow);  red += __shfl_xor(red, 32);
            #pragma unroll
            for (int r = 6; r < kC; ++r) step(wr + r * kRow);
            fold();
        } else {                                  // tail chunk (guarded)
            const int t0 = ck * kC;
            for (int r = 0; r < kC; ++r) {
                if (t0 + r >= Tb) break;
                step(wr + r * kRow);
            }
        }
    };

    // preamble: stage chunk 0, prefetch chunk 1
    if (wv > 0) {
        load_chunk(0, rgE);
        store_chunk(0, rgE);
        load_chunk(1, rgO);
    }
    __syncthreads();

    for (int ck = 0; ck < nck; ck += 2) {
        // even chunk ck: consumer reads slot 0; producers fill slot 1
        if (wv == 0) {
            consumer_chunk(ck);
        } else {
            if (ck + 1 < nck) store_chunk(ck + 1, rgO);
            load_chunk(ck + 2, rgE);               // guarded by t < Tb inside
            if (wv == 1) reduce_lse(ck);
        }
        __syncthreads();
        // odd chunk ck+1: consumer reads slot 1; producers fill slot 0
        if (ck + 1 < nck) {
            if (wv == 0) {
                consumer_chunk(ck + 1);
            } else {
                if (ck + 2 < nck) store_chunk(ck + 2, rgE);
                load_chunk(ck + 3, rgO);
                if (wv == 1) reduce_lse(ck + 1);
            }
            __syncthreads();
        }
    }

    // ---------------- epilogue ----------------
    float* afin = (float*)wbuf;    // wbuf is dead now
    if (wv == 0 && lane <= 50) {
        #pragma unroll
        for (int i = 0; i < 16; ++i) afin[16 * lane + i] = a[i];
    }
    if (wv == 1 && lane == 0) sLd = Ld;
    __syncthreads();
    if (tid == 0) {
        const float tail = afin[Sb - 2] + afin[Sb - 1];
        const double la = (double)__logf(tail) + Ct - sLd;  // -inf if tail==0
        float loss = 0.f;
        if (la > -5e29) loss = (float)(-la / (double)Lb);
        loss_ws[b] = loss;
    }
}

__global__ void mean64_kernel(const float* __restrict__ loss_ws,
                              float* __restrict__ out) {
    float v = loss_ws[threadIdx.x];
    #pragma unroll
    for (int off = 32; off > 0; off >>= 1) v += __shfl_xor(v, off);
    if (threadIdx.x == 0) out[0] = v * (1.0f / 64.0f);
}

extern "C" void kernel_launch(void* const* d_in, const int* in_sizes, int n_in,
                              void* d_out, int out_size, void* d_ws, size_t ws_size,
                              hipStream_t stream) {
    const float* attn      = (const float*)d_in[0];
    const int*   text_lens = (const int*)d_in[1];
    const int*   mel_lens  = (const int*)d_in[2];
    float* loss_ws = (float*)d_ws;

    ctc_forward_kernel<<<kB, 256, 0, stream>>>(attn, text_lens, mel_lens, loss_ws);
    mean64_kernel<<<1, 64, 0, stream>>>(loss_ws, (float*)d_out);
}